// Round 4
// baseline (746.894 us; speedup 1.0000x reference)
//
#include <hip/hip_runtime.h>
#include <hip/hip_bf16.h>

// EdgeBlock: out[e] = relu(concat(edge[e], node[recv[e]], node[send[e]], g) @ W1 + b1) @ W2 + b2
// Round 4: decouple gathers from VGPRs via global_load_lds (per-lane gather addresses,
// wave-uniform LDS dest), per-wave double-buffered node tiles, counted vmcnt waits
// (T3/T4 pattern), straight-line macros (no lambdas -> no scratch), vectorized stores
// through an LDS re-transpose. Nodes pre-converted to bf16 (gathers = direct MFMA frags).

typedef __bf16 bf16x8 __attribute__((ext_vector_type(8)));
typedef float f32x4 __attribute__((ext_vector_type(4)));

#define K1 192
#define GRID_MAIN 1024
#define WS_NODEBF_OFF 66560

__global__ void prep_kernel(const float* __restrict__ W1, const float* __restrict__ b1,
                            const float* __restrict__ W2, const float* __restrict__ gattr,
                            __bf16* __restrict__ W1T, __bf16* __restrict__ W2T,
                            float* __restrict__ g1) {
    int tid = blockIdx.x * blockDim.x + threadIdx.x;
    if (tid < 128 * 192) {
        int n = tid / 192, k = tid % 192;
        W1T[n * 192 + k] = (__bf16)W1[k * 128 + n];
    } else if (tid < 128 * 192 + 64 * 128) {
        int t = tid - 128 * 192;
        int n = t / 128, k = t % 128;
        W2T[n * 128 + k] = (__bf16)W2[k * 64 + n];
    } else if (tid < 128 * 192 + 64 * 128 + 128) {
        int n = tid - (128 * 192 + 64 * 128);
        float acc = b1[n];
        for (int j = 0; j < 64; ++j) acc += gattr[j] * W1[(192 + j) * 128 + n];
        g1[n] = acc;
    }
}

__global__ __launch_bounds__(256) void node_conv_kernel(const float* __restrict__ nf,
                                                        __bf16* __restrict__ nb, int n8) {
    int t = blockIdx.x * blockDim.x + threadIdx.x;  // one thread per 8 floats
    if (t < n8) {
        f32x4 a = *(const f32x4*)(nf + (long)t * 8);
        f32x4 b = *(const f32x4*)(nf + (long)t * 8 + 4);
        bf16x8 o;
#pragma unroll
        for (int j = 0; j < 4; ++j) { o[j] = (__bf16)a[j]; o[4 + j] = (__bf16)b[j]; }
        *(bf16x8*)(nb + (long)t * 8) = o;
    }
}

__device__ __forceinline__ f32x4 mk4(float v) {
    f32x4 r; r[0] = v; r[1] = v; r[2] = v; r[3] = v; return r;
}

// async 16B DMA: per-lane global addr, LDS dest = uniform base + lane*16
#define GLL16(GP, LP) __builtin_amdgcn_global_load_lds(                     \
    (const __attribute__((address_space(1))) void*)(GP),                    \
    (__attribute__((address_space(3))) void*)(LP), 16, 0, 0)

// stage recv+send rows of one 16-edge tile into nlds[w][BUF] (4KB, 4 DMAs)
#define ISSUE_GATHER(BUF, RR, SS) {                                         \
    const __bf16* pr_ = node_bf + ((long)(RR) << 6) + g * 8;                \
    const __bf16* ps_ = node_bf + ((long)(SS) << 6) + g * 8;                \
    __bf16* lb_ = &nlds[w][BUF][0];                                         \
    GLL16(pr_,      lb_);                                                   \
    GLL16(pr_ + 32, lb_ + 512);                                             \
    GLL16(ps_,      lb_ + 1024);                                            \
    GLL16(ps_ + 32, lb_ + 1536);                                            \
}

// edge rows -> VGPR stage (4 x dwordx4, coalesced)
#define ISSUE_EDGES(EST, ROWL) {                                            \
    const float* pe_ = edge_feats + ((long)(ROWL) << 6) + g * 8;            \
    EST[0] = *(const f32x4*)(pe_);                                          \
    EST[1] = *(const f32x4*)(pe_ + 4);                                      \
    EST[2] = *(const f32x4*)(pe_ + 32);                                     \
    EST[3] = *(const f32x4*)(pe_ + 36);                                     \
}

#define TILEROW(I, DST) {                                                   \
    long r_ = ((long)blockIdx.x + (long)(I) * G) * 64 + w * 16 + c;         \
    if (r_ > (long)E - 1) r_ = (long)E - 1;                                 \
    DST = r_;                                                               \
}

#define COMPUTE_TILE(BUF, EST, TI) {                                        \
    bf16x8 fr0 = *(const bf16x8*)&nlds[w][BUF][lane * 8];                   \
    bf16x8 fr1 = *(const bf16x8*)&nlds[w][BUF][512 + lane * 8];             \
    bf16x8 fs0 = *(const bf16x8*)&nlds[w][BUF][1024 + lane * 8];            \
    bf16x8 fs1 = *(const bf16x8*)&nlds[w][BUF][1536 + lane * 8];            \
    bf16x8 fe0, fe1;                                                        \
    _Pragma("unroll")                                                       \
    for (int j = 0; j < 4; ++j) {                                           \
        fe0[j] = (__bf16)EST[0][j]; fe0[4 + j] = (__bf16)EST[1][j];         \
        fe1[j] = (__bf16)EST[2][j]; fe1[4 + j] = (__bf16)EST[3][j];         \
    }                                                                       \
    f32x4 acc[8];                                                           \
    _Pragma("unroll")                                                       \
    for (int nt = 0; nt < 8; ++nt) acc[nt] = mk4(gv[nt]);                   \
    _Pragma("unroll")                                                       \
    for (int nt = 0; nt < 8; ++nt) {                                        \
        const __bf16* wb_ = W1T + (nt * 16 + c) * K1 + g * 8;               \
        acc[nt] = __builtin_amdgcn_mfma_f32_16x16x32_bf16(fe0, *(const bf16x8*)(wb_),       acc[nt], 0, 0, 0); \
        acc[nt] = __builtin_amdgcn_mfma_f32_16x16x32_bf16(fe1, *(const bf16x8*)(wb_ + 32),  acc[nt], 0, 0, 0); \
        acc[nt] = __builtin_amdgcn_mfma_f32_16x16x32_bf16(fr0, *(const bf16x8*)(wb_ + 64),  acc[nt], 0, 0, 0); \
        acc[nt] = __builtin_amdgcn_mfma_f32_16x16x32_bf16(fr1, *(const bf16x8*)(wb_ + 96),  acc[nt], 0, 0, 0); \
        acc[nt] = __builtin_amdgcn_mfma_f32_16x16x32_bf16(fs0, *(const bf16x8*)(wb_ + 128), acc[nt], 0, 0, 0); \
        acc[nt] = __builtin_amdgcn_mfma_f32_16x16x32_bf16(fs1, *(const bf16x8*)(wb_ + 160), acc[nt], 0, 0, 0); \
    }                                                                       \
    _Pragma("unroll")                                                       \
    for (int nt = 0; nt < 8; ++nt)                                          \
        _Pragma("unroll")                                                   \
        for (int r = 0; r < 4; ++r) {                                       \
            float v_ = acc[nt][r]; v_ = v_ > 0.f ? v_ : 0.f;                \
            h_lds[w][g * 4 + r][nt * 16 + c] = (__bf16)v_;                  \
        }                                                                   \
    asm volatile("s_waitcnt lgkmcnt(0)" ::: "memory");                      \
    f32x4 acc2[4];                                                          \
    _Pragma("unroll")                                                       \
    for (int nt = 0; nt < 4; ++nt) acc2[nt] = mk4(b2v[nt]);                 \
    _Pragma("unroll")                                                       \
    for (int ks = 0; ks < 4; ++ks) {                                        \
        bf16x8 ah_ = *(const bf16x8*)&h_lds[w][c][ks * 32 + g * 8];         \
        _Pragma("unroll")                                                   \
        for (int nt = 0; nt < 4; ++nt) {                                    \
            bf16x8 wb2_ = *(const bf16x8*)(W2T + (nt * 16 + c) * 128 + ks * 32 + g * 8); \
            acc2[nt] = __builtin_amdgcn_mfma_f32_16x16x32_bf16(ah_, wb2_, acc2[nt], 0, 0, 0); \
        }                                                                   \
    }                                                                       \
    /* re-transpose to row-major f32 [16][68] in the same LDS bytes, then 4 x dwordx4 store */ \
    {                                                                       \
        float* op_ = (float*)&h_lds[w][0][0];                               \
        _Pragma("unroll")                                                   \
        for (int nt = 0; nt < 4; ++nt)                                      \
            _Pragma("unroll")                                               \
            for (int r = 0; r < 4; ++r)                                     \
                op_[(g * 4 + r) * 68 + nt * 16 + c] = acc2[nt][r];          \
        asm volatile("s_waitcnt lgkmcnt(0)" ::: "memory");                  \
        long tb_ = ((long)blockIdx.x + (long)(TI) * G) * 64 + w * 16;       \
        long rowc_ = tb_ + c;                                               \
        if (rowc_ < E) {                                                    \
            float* po_ = out + rowc_ * 64 + g * 16;                         \
            const float* ip_ = op_ + c * 68 + g * 16;                       \
            *(f32x4*)(po_)      = *(const f32x4*)(ip_);                     \
            *(f32x4*)(po_ + 4)  = *(const f32x4*)(ip_ + 4);                 \
            *(f32x4*)(po_ + 8)  = *(const f32x4*)(ip_ + 8);                 \
            *(f32x4*)(po_ + 12) = *(const f32x4*)(ip_ + 12);                \
        }                                                                   \
    }                                                                       \
}

__global__ __launch_bounds__(256, 3) void edge_mlp_kernel(
    const float* __restrict__ edge_feats, const __bf16* __restrict__ node_bf,
    const int* __restrict__ senders, const int* __restrict__ receivers,
    const __bf16* __restrict__ W1T, const __bf16* __restrict__ W2T,
    const float* __restrict__ g1, const float* __restrict__ b2,
    float* __restrict__ out, int E)
{
    __shared__ __bf16 nlds[4][2][2048];   // per-wave double-buffered node tiles (32 KB)
    __shared__ __bf16 h_lds[4][16][136];  // per-wave hidden transpose / out staging (17 KB)

    const int lane = threadIdx.x & 63;
    const int w    = threadIdx.x >> 6;
    const int c    = lane & 15;
    const int g    = lane >> 4;
    const int G    = gridDim.x;

    float gv[8], b2v[4];
#pragma unroll
    for (int nt = 0; nt < 8; ++nt) gv[nt] = g1[nt * 16 + c];
#pragma unroll
    for (int nt = 0; nt < 4; ++nt) b2v[nt] = b2[nt * 16 + c];

    const int numTiles = (E + 63) >> 6;
    const int numMine  = (numTiles - blockIdx.x + G - 1) / G;
    if (numMine <= 0) return;

    f32x4 estA[4], estB[4];
    long rowA, rowB;
    int iRa, iSa, iRb, iSb;

    // prologue: tile 0 -> buf0/estA; idx for tile 1 -> (iRb,iSb)
    TILEROW(0, rowA);
    iRa = receivers[rowA]; iSa = senders[rowA];
    ISSUE_GATHER(0, iRa, iSa);
    ISSUE_EDGES(estA, rowA);
    TILEROW(1, rowB);
    iRb = receivers[rowB]; iSb = senders[rowB];

    int i = 0;
    while (true) {
        // phase A: compute tile i (buf0/estA); prefetch tile i+1 -> buf1/estB
        const bool more1 = (i + 1 < numMine);
        if (more1) {
            ISSUE_GATHER(1, iRb, iSb);
            ISSUE_EDGES(estB, rowB);
            TILEROW(i + 2, rowA);
            iRa = receivers[rowA]; iSa = senders[rowA];
            asm volatile("s_waitcnt vmcnt(10)" ::: "memory");  // keep the 10 just-issued in flight
        } else {
            asm volatile("s_waitcnt vmcnt(0)" ::: "memory");
        }
        COMPUTE_TILE(0, estA, i);
        if (!more1) break;

        // phase B: compute tile i+1 (buf1/estB); prefetch tile i+2 -> buf0/estA
        const bool more2 = (i + 2 < numMine);
        if (more2) {
            ISSUE_GATHER(0, iRa, iSa);
            ISSUE_EDGES(estA, rowA);
            TILEROW(i + 3, rowB);
            iRb = receivers[rowB]; iSb = senders[rowB];
            asm volatile("s_waitcnt vmcnt(10)" ::: "memory");
        } else {
            asm volatile("s_waitcnt vmcnt(0)" ::: "memory");
        }
        COMPUTE_TILE(1, estB, i + 1);
        if (!more2) break;
        i += 2;
    }
}

// fallback (small ws): round-1 kernel, f32 node gathers, no pipeline
__global__ __launch_bounds__(256) void edge_mlp_fallback(
    const float* __restrict__ edge_feats, const float* __restrict__ node_feats,
    const int* __restrict__ senders, const int* __restrict__ receivers,
    const __bf16* __restrict__ W1T, const __bf16* __restrict__ W2T,
    const float* __restrict__ g1, const float* __restrict__ b2,
    float* __restrict__ out, int E)
{
    __shared__ __bf16 h_lds[64][136];
    const int e0 = blockIdx.x * 64;
    const int lane = threadIdx.x & 63;
    const int w = threadIdx.x >> 6;
    const int c = lane & 15;
    const int g = lane >> 4;
    const float* pe[4]; const float* pr[4]; const float* ps[4];
#pragma unroll
    for (int mt = 0; mt < 4; ++mt) {
        int row = e0 + mt * 16 + c;
        if (row > E - 1) row = E - 1;
        pe[mt] = edge_feats + (long)row * 64;
        pr[mt] = node_feats + (long)receivers[row] * 64;
        ps[mt] = node_feats + (long)senders[row] * 64;
    }
    f32x4 acc[4][2];
#pragma unroll
    for (int nt = 0; nt < 2; ++nt) {
        float v = g1[(2 * w + nt) * 16 + c];
#pragma unroll
        for (int mt = 0; mt < 4; ++mt) acc[mt][nt] = mk4(v);
    }
#pragma unroll
    for (int ks = 0; ks < 6; ++ks) {
        bf16x8 bfr[2];
#pragma unroll
        for (int nt = 0; nt < 2; ++nt)
            bfr[nt] = *(const bf16x8*)(W1T + ((2 * w + nt) * 16 + c) * K1 + ks * 32 + g * 8);
#pragma unroll
        for (int mt = 0; mt < 4; ++mt) {
            const float* base = (ks < 2) ? pe[mt] : (ks < 4) ? pr[mt] : ps[mt];
            const float* p = base + (ks & 1) * 32 + g * 8;
            f32x4 lo = *(const f32x4*)p;
            f32x4 hi = *(const f32x4*)(p + 4);
            bf16x8 a;
#pragma unroll
            for (int j = 0; j < 4; ++j) { a[j] = (__bf16)lo[j]; a[4 + j] = (__bf16)hi[j]; }
#pragma unroll
            for (int nt = 0; nt < 2; ++nt)
                acc[mt][nt] = __builtin_amdgcn_mfma_f32_16x16x32_bf16(a, bfr[nt], acc[mt][nt], 0, 0, 0);
        }
    }
#pragma unroll
    for (int mt = 0; mt < 4; ++mt)
#pragma unroll
        for (int nt = 0; nt < 2; ++nt)
#pragma unroll
            for (int r = 0; r < 4; ++r) {
                float v = acc[mt][nt][r];
                v = v > 0.f ? v : 0.f;
                h_lds[mt * 16 + g * 4 + r][(2 * w + nt) * 16 + c] = (__bf16)v;
            }
    __syncthreads();
    f32x4 acc2[4];
    {
        float bv = b2[w * 16 + c];
#pragma unroll
        for (int mt = 0; mt < 4; ++mt) acc2[mt] = mk4(bv);
    }
#pragma unroll
    for (int ks = 0; ks < 4; ++ks) {
        bf16x8 b2f = *(const bf16x8*)(W2T + (w * 16 + c) * 128 + ks * 32 + g * 8);
#pragma unroll
        for (int mt = 0; mt < 4; ++mt) {
            bf16x8 a2 = *(const bf16x8*)&h_lds[mt * 16 + c][ks * 32 + g * 8];
            acc2[mt] = __builtin_amdgcn_mfma_f32_16x16x32_bf16(a2, b2f, acc2[mt], 0, 0, 0);
        }
    }
#pragma unroll
    for (int mt = 0; mt < 4; ++mt)
#pragma unroll
        for (int r = 0; r < 4; ++r) {
            int row = e0 + mt * 16 + g * 4 + r;
            if (row < E) out[(long)row * 64 + w * 16 + c] = acc2[mt][r];
        }
}

extern "C" void kernel_launch(void* const* d_in, const int* in_sizes, int n_in,
                              void* d_out, int out_size, void* d_ws, size_t ws_size,
                              hipStream_t stream) {
    const float* edge_feats = (const float*)d_in[0];
    const float* node_feats = (const float*)d_in[1];
    const float* gattr      = (const float*)d_in[2];
    const int*   senders    = (const int*)d_in[3];
    const int*   receivers  = (const int*)d_in[4];
    const float* W1         = (const float*)d_in[5];
    const float* b1         = (const float*)d_in[6];
    const float* W2         = (const float*)d_in[7];
    const float* b2         = (const float*)d_in[8];
    float* out = (float*)d_out;

    const int E = in_sizes[3];        // N_EDGES
    const int N = in_sizes[1] / 64;   // N_NODES

    char* ws = (char*)d_ws;
    __bf16* W1T = (__bf16*)ws;
    __bf16* W2T = (__bf16*)(ws + 49152);
    float*  g1  = (float*)(ws + 49152 + 16384);
    __bf16* nodeBF = (__bf16*)(ws + WS_NODEBF_OFF);

    const size_t ws_needed = (size_t)WS_NODEBF_OFF + (size_t)N * 64 * 2;
    const bool useNB = ws_size >= ws_needed;

    int prep_total = 128 * 192 + 64 * 128 + 128;
    prep_kernel<<<(prep_total + 255) / 256, 256, 0, stream>>>(W1, b1, W2, gattr, W1T, W2T, g1);

    const int numTiles = (E + 63) / 64;
    if (useNB) {
        int n8 = N * 8;
        node_conv_kernel<<<(n8 + 255) / 256, 256, 0, stream>>>(node_feats, nodeBF, n8);
        int grid = numTiles < GRID_MAIN ? numTiles : GRID_MAIN;
        edge_mlp_kernel<<<grid, 256, 0, stream>>>(edge_feats, nodeBF, senders, receivers,
                                                  W1T, W2T, g1, b2, out, E);
    } else {
        edge_mlp_fallback<<<numTiles, 256, 0, stream>>>(edge_feats, node_feats, senders, receivers,
                                                        W1T, W2T, g1, b2, out, E);
    }
}

// Round 5
// 125.386 us; speedup vs baseline: 5.9568x; 5.9568x over previous
//
#include <hip/hip_runtime.h>
#include <hip/hip_bf16.h>

// EdgeBlock: out[e] = relu(concat(edge[e], node[recv[e]], node[send[e]], g) @ W1 + b1) @ W2 + b2
// Round 5: minimize divergent VMEM instructions (theory: TA/address-processing bound).
//  - weights in frag-order ws tables -> 16 fully-coalesced loads ONCE per block (grid-stride)
//  - per tile: each wave gathers only its own 16 edges (~10 VMEM instr), writes MFMA
//    fragments lane-linearly to a shared frag-order A-tile in LDS (conflict-free b128)
//  - compute uses round-1's verified decomposition (wave = 64 edges x 32 hid cols)
//  - nodes pre-converted to bf16 (half gather bytes/lines); global-attr prefolded (K=192)

typedef __bf16 bf16x8 __attribute__((ext_vector_type(8)));
typedef float f32x4 __attribute__((ext_vector_type(4)));

#define GRID_MAIN 2048
// ws layout:
//   [0, 49152)       W1F bf16 frag-order: [((w*2+nt2)*6+f)*64 + c+16g]*8+j = W1[f*32+g*8+j][w*32+nt2*16+c]
//   [49152, 65536)   W2F bf16 frag-order: [(w*4+ks)*64 + c+16g]*8+j      = W2[ks*32+g*8+j][w*16+c]
//   [65536, 66048)   g1 f32 [128] = b1 + global_attr @ W1[192:256]
//   [66560, ...)     node_bf16 [N][64]
#define WS_NODEBF_OFF 66560

__global__ void prep_kernel(const float* __restrict__ W1, const float* __restrict__ b1,
                            const float* __restrict__ W2, const float* __restrict__ gattr,
                            __bf16* __restrict__ W1F, __bf16* __restrict__ W2F,
                            float* __restrict__ g1) {
    int tid = blockIdx.x * blockDim.x + threadIdx.x;
    if (tid < 128 * 192) {
        int n = tid / 192, k = tid % 192;
        int w = n >> 5, nt2 = (n >> 4) & 1, c = n & 15;
        int f = k >> 5, g = (k >> 3) & 3, j = k & 7;
        W1F[((((w * 2 + nt2) * 6 + f) * 64) + c + 16 * g) * 8 + j] = (__bf16)W1[k * 128 + n];
    } else if (tid < 128 * 192 + 64 * 128) {
        int t = tid - 128 * 192;
        int n = t / 128, k = t % 128;
        int w = n >> 4, c = n & 15;
        int ks = k >> 5, g = (k >> 3) & 3, j = k & 7;
        W2F[(((w * 4 + ks) * 64) + c + 16 * g) * 8 + j] = (__bf16)W2[k * 64 + n];
    } else if (tid < 128 * 192 + 64 * 128 + 128) {
        int n = tid - (128 * 192 + 64 * 128);
        float acc = b1[n];
        for (int j = 0; j < 64; ++j) acc += gattr[j] * W1[(192 + j) * 128 + n];
        g1[n] = acc;
    }
}

__global__ __launch_bounds__(256) void node_conv_kernel(const float* __restrict__ nf,
                                                        __bf16* __restrict__ nb, int n8) {
    int t = blockIdx.x * blockDim.x + threadIdx.x;
    if (t < n8) {
        f32x4 a = *(const f32x4*)(nf + (long)t * 8);
        f32x4 b = *(const f32x4*)(nf + (long)t * 8 + 4);
        bf16x8 o;
#pragma unroll
        for (int j = 0; j < 4; ++j) { o[j] = (__bf16)a[j]; o[4 + j] = (__bf16)b[j]; }
        *(bf16x8*)(nb + (long)t * 8) = o;
    }
}

__device__ __forceinline__ f32x4 mk4(float v) {
    f32x4 r; r[0] = v; r[1] = v; r[2] = v; r[3] = v; return r;
}

__device__ __forceinline__ bf16x8 cvt8(f32x4 lo, f32x4 hi) {
    bf16x8 t;
#pragma unroll
    for (int j = 0; j < 4; ++j) { t[j] = (__bf16)lo[j]; t[4 + j] = (__bf16)hi[j]; }
    return t;
}

__global__ __launch_bounds__(256) void edge_mlp_kernel(
    const float* __restrict__ edge_feats, const __bf16* __restrict__ node_bf,
    const int* __restrict__ senders, const int* __restrict__ receivers,
    const __bf16* __restrict__ W1F, const __bf16* __restrict__ W2F,
    const float* __restrict__ g1, const float* __restrict__ b2,
    float* __restrict__ out, int E, int numTiles)
{
    // frag-order A tile: [mt=4][f=6][lane=64] x 16B  (24 KB)
    __shared__ __bf16 A_lds[4 * 6 * 64 * 8];
    // hidden transpose tile (17.4 KB)
    __shared__ __bf16 h_lds[64][136];

    const int lane = threadIdx.x & 63;
    const int w    = threadIdx.x >> 6;
    const int c    = lane & 15;
    const int g    = lane >> 4;
    const int G    = gridDim.x;

    // ---- pinned weights: 16 coalesced dwordx4 loads, once per block ----
    bf16x8 wb1[2][6];
#pragma unroll
    for (int nt2 = 0; nt2 < 2; ++nt2)
#pragma unroll
        for (int f = 0; f < 6; ++f)
            wb1[nt2][f] = *(const bf16x8*)(W1F + (((w * 2 + nt2) * 6 + f) * 64 + lane) * 8);
    bf16x8 wb2[4];
#pragma unroll
    for (int ks = 0; ks < 4; ++ks)
        wb2[ks] = *(const bf16x8*)(W2F + ((w * 4 + ks) * 64 + lane) * 8);
    const float g1v0 = g1[w * 32 + c];
    const float g1v1 = g1[w * 32 + 16 + c];
    const float b2v  = b2[w * 16 + c];

    // ---- idx prefetch for first tile ----
    int curR = 0, curS = 0;
    {
        long rc = (long)blockIdx.x * 64 + w * 16 + c;
        if (rc > (long)E - 1) rc = (long)E - 1;
        curR = receivers[rc]; curS = senders[rc];
    }

    for (int t = blockIdx.x; t < numTiles; t += G) {
        // ---- gather phase: this wave's 16 edges ----
        const __bf16* pr = node_bf + ((long)curR << 6) + g * 8;
        const __bf16* ps = node_bf + ((long)curS << 6) + g * 8;
        bf16x8 nr0 = *(const bf16x8*)(pr);
        bf16x8 nr1 = *(const bf16x8*)(pr + 32);
        bf16x8 ns0 = *(const bf16x8*)(ps);
        bf16x8 ns1 = *(const bf16x8*)(ps + 32);

        long rowc = (long)t * 64 + w * 16 + c;
        if (rowc > (long)E - 1) rowc = (long)E - 1;
        const float* pe = edge_feats + (rowc << 6) + g * 8;
        f32x4 e0a = *(const f32x4*)(pe);
        f32x4 e0b = *(const f32x4*)(pe + 4);
        f32x4 e1a = *(const f32x4*)(pe + 32);
        f32x4 e1b = *(const f32x4*)(pe + 36);

        // prefetch next tile's indices (hides idx->gather round trip)
        int tn = t + G;
        if (tn < numTiles) {
            long rc2 = (long)tn * 64 + w * 16 + c;
            if (rc2 > (long)E - 1) rc2 = (long)E - 1;
            curR = receivers[rc2]; curS = senders[rc2];
        }

        // write fragments lane-linearly (conflict-free b128)
        __bf16* ab = A_lds + (w * 6) * 64 * 8 + lane * 8;
        *(bf16x8*)(ab)           = cvt8(e0a, e0b);   // f=0 (edge k 0-31)
        *(bf16x8*)(ab + 512)     = cvt8(e1a, e1b);   // f=1 (edge k 32-63)
        *(bf16x8*)(ab + 1024)    = nr0;              // f=2 (recv k 0-31)
        *(bf16x8*)(ab + 1536)    = nr1;              // f=3
        *(bf16x8*)(ab + 2048)    = ns0;              // f=4 (send)
        *(bf16x8*)(ab + 2560)    = ns1;              // f=5
        __syncthreads();

        // ---- GEMM1: wave owns cols [w*32, w*32+32) for all 64 edges ----
        f32x4 acc0[4], acc1[4];
#pragma unroll
        for (int mt = 0; mt < 4; ++mt) { acc0[mt] = mk4(g1v0); acc1[mt] = mk4(g1v1); }
#pragma unroll
        for (int mt = 0; mt < 4; ++mt)
#pragma unroll
            for (int f = 0; f < 6; ++f) {
                bf16x8 a = *(const bf16x8*)(A_lds + ((mt * 6 + f) * 64 + lane) * 8);
                acc0[mt] = __builtin_amdgcn_mfma_f32_16x16x32_bf16(a, wb1[0][f], acc0[mt], 0, 0, 0);
                acc1[mt] = __builtin_amdgcn_mfma_f32_16x16x32_bf16(a, wb1[1][f], acc1[mt], 0, 0, 0);
            }

        // relu -> h_lds (h[row = mt*16+g*4+r][col = w*32 + {0,16} + c])
#pragma unroll
        for (int mt = 0; mt < 4; ++mt)
#pragma unroll
            for (int r = 0; r < 4; ++r) {
                float v0 = acc0[mt][r]; v0 = v0 > 0.f ? v0 : 0.f;
                float v1 = acc1[mt][r]; v1 = v1 > 0.f ? v1 : 0.f;
                h_lds[mt * 16 + g * 4 + r][w * 32 + c]      = (__bf16)v0;
                h_lds[mt * 16 + g * 4 + r][w * 32 + 16 + c] = (__bf16)v1;
            }
        __syncthreads();

        // ---- GEMM2: wave owns out cols [w*16, w*16+16) for all 64 edges ----
        f32x4 acc2[4];
#pragma unroll
        for (int mt = 0; mt < 4; ++mt) acc2[mt] = mk4(b2v);
#pragma unroll
        for (int mt = 0; mt < 4; ++mt)
#pragma unroll
            for (int ks = 0; ks < 4; ++ks) {
                bf16x8 ah = *(const bf16x8*)&h_lds[mt * 16 + c][ks * 32 + g * 8];
                acc2[mt] = __builtin_amdgcn_mfma_f32_16x16x32_bf16(ah, wb2[ks], acc2[mt], 0, 0, 0);
            }

        // stores (4-row x 64B segments per instr)
#pragma unroll
        for (int mt = 0; mt < 4; ++mt)
#pragma unroll
            for (int r = 0; r < 4; ++r) {
                long orow = (long)t * 64 + mt * 16 + g * 4 + r;
                if (orow < E) out[orow * 64 + w * 16 + c] = acc2[mt][r];
            }
        __syncthreads();   // protect A_lds/h_lds reuse next iteration
    }
}

// fallback (ws too small for node table): same structure minus node_bf (f32 node gathers)
__global__ __launch_bounds__(256) void edge_mlp_fallback(
    const float* __restrict__ edge_feats, const float* __restrict__ node_feats,
    const int* __restrict__ senders, const int* __restrict__ receivers,
    const __bf16* __restrict__ W1F, const __bf16* __restrict__ W2F,
    const float* __restrict__ g1, const float* __restrict__ b2,
    float* __restrict__ out, int E, int numTiles)
{
    __shared__ __bf16 A_lds[4 * 6 * 64 * 8];
    __shared__ __bf16 h_lds[64][136];
    const int lane = threadIdx.x & 63;
    const int w = threadIdx.x >> 6;
    const int c = lane & 15;
    const int g = lane >> 4;
    const int G = gridDim.x;

    bf16x8 wb1[2][6];
#pragma unroll
    for (int nt2 = 0; nt2 < 2; ++nt2)
#pragma unroll
        for (int f = 0; f < 6; ++f)
            wb1[nt2][f] = *(const bf16x8*)(W1F + (((w * 2 + nt2) * 6 + f) * 64 + lane) * 8);
    bf16x8 wb2[4];
#pragma unroll
    for (int ks = 0; ks < 4; ++ks)
        wb2[ks] = *(const bf16x8*)(W2F + ((w * 4 + ks) * 64 + lane) * 8);
    const float g1v0 = g1[w * 32 + c];
    const float g1v1 = g1[w * 32 + 16 + c];
    const float b2v  = b2[w * 16 + c];

    for (int t = blockIdx.x; t < numTiles; t += G) {
        long rowc = (long)t * 64 + w * 16 + c;
        if (rowc > (long)E - 1) rowc = (long)E - 1;
        int iR = receivers[rowc], iS = senders[rowc];
        const float* pr = node_feats + ((long)iR << 6) + g * 8;
        const float* ps = node_feats + ((long)iS << 6) + g * 8;
        const float* pe = edge_feats + (rowc << 6) + g * 8;
        f32x4 e0a = *(const f32x4*)(pe),      e0b = *(const f32x4*)(pe + 4);
        f32x4 e1a = *(const f32x4*)(pe + 32), e1b = *(const f32x4*)(pe + 36);
        f32x4 r0a = *(const f32x4*)(pr),      r0b = *(const f32x4*)(pr + 4);
        f32x4 r1a = *(const f32x4*)(pr + 32), r1b = *(const f32x4*)(pr + 36);
        f32x4 s0a = *(const f32x4*)(ps),      s0b = *(const f32x4*)(ps + 4);
        f32x4 s1a = *(const f32x4*)(ps + 32), s1b = *(const f32x4*)(ps + 36);

        __bf16* ab = A_lds + (w * 6) * 64 * 8 + lane * 8;
        *(bf16x8*)(ab)        = cvt8(e0a, e0b);
        *(bf16x8*)(ab + 512)  = cvt8(e1a, e1b);
        *(bf16x8*)(ab + 1024) = cvt8(r0a, r0b);
        *(bf16x8*)(ab + 1536) = cvt8(r1a, r1b);
        *(bf16x8*)(ab + 2048) = cvt8(s0a, s0b);
        *(bf16x8*)(ab + 2560) = cvt8(s1a, s1b);
        __syncthreads();

        f32x4 acc0[4], acc1[4];
#pragma unroll
        for (int mt = 0; mt < 4; ++mt) { acc0[mt] = mk4(g1v0); acc1[mt] = mk4(g1v1); }
#pragma unroll
        for (int mt = 0; mt < 4; ++mt)
#pragma unroll
            for (int f = 0; f < 6; ++f) {
                bf16x8 a = *(const bf16x8*)(A_lds + ((mt * 6 + f) * 64 + lane) * 8);
                acc0[mt] = __builtin_amdgcn_mfma_f32_16x16x32_bf16(a, wb1[0][f], acc0[mt], 0, 0, 0);
                acc1[mt] = __builtin_amdgcn_mfma_f32_16x16x32_bf16(a, wb1[1][f], acc1[mt], 0, 0, 0);
            }
#pragma unroll
        for (int mt = 0; mt < 4; ++mt)
#pragma unroll
            for (int r = 0; r < 4; ++r) {
                float v0 = acc0[mt][r]; v0 = v0 > 0.f ? v0 : 0.f;
                float v1 = acc1[mt][r]; v1 = v1 > 0.f ? v1 : 0.f;
                h_lds[mt * 16 + g * 4 + r][w * 32 + c]      = (__bf16)v0;
                h_lds[mt * 16 + g * 4 + r][w * 32 + 16 + c] = (__bf16)v1;
            }
        __syncthreads();

        f32x4 acc2[4];
#pragma unroll
        for (int mt = 0; mt < 4; ++mt) acc2[mt] = mk4(b2v);
#pragma unroll
        for (int mt = 0; mt < 4; ++mt)
#pragma unroll
            for (int ks = 0; ks < 4; ++ks) {
                bf16x8 ah = *(const bf16x8*)&h_lds[mt * 16 + c][ks * 32 + g * 8];
                acc2[mt] = __builtin_amdgcn_mfma_f32_16x16x32_bf16(ah, wb2[ks], acc2[mt], 0, 0, 0);
            }
#pragma unroll
        for (int mt = 0; mt < 4; ++mt)
#pragma unroll
            for (int r = 0; r < 4; ++r) {
                long orow = (long)t * 64 + mt * 16 + g * 4 + r;
                if (orow < E) out[orow * 64 + w * 16 + c] = acc2[mt][r];
            }
        __syncthreads();
    }
}

extern "C" void kernel_launch(void* const* d_in, const int* in_sizes, int n_in,
                              void* d_out, int out_size, void* d_ws, size_t ws_size,
                              hipStream_t stream) {
    const float* edge_feats = (const float*)d_in[0];
    const float* node_feats = (const float*)d_in[1];
    const float* gattr      = (const float*)d_in[2];
    const int*   senders    = (const int*)d_in[3];
    const int*   receivers  = (const int*)d_in[4];
    const float* W1         = (const float*)d_in[5];
    const float* b1         = (const float*)d_in[6];
    const float* W2         = (const float*)d_in[7];
    const float* b2         = (const float*)d_in[8];
    float* out = (float*)d_out;

    const int E = in_sizes[3];        // N_EDGES
    const int N = in_sizes[1] / 64;   // N_NODES

    char* ws = (char*)d_ws;
    __bf16* W1F = (__bf16*)ws;
    __bf16* W2F = (__bf16*)(ws + 49152);
    float*  g1  = (float*)(ws + 49152 + 16384);
    __bf16* nodeBF = (__bf16*)(ws + WS_NODEBF_OFF);

    const size_t ws_needed = (size_t)WS_NODEBF_OFF + (size_t)N * 64 * 2;
    const bool useNB = ws_size >= ws_needed;

    int prep_total = 128 * 192 + 64 * 128 + 128;
    prep_kernel<<<(prep_total + 255) / 256, 256, 0, stream>>>(W1, b1, W2, gattr, W1F, W2F, g1);

    const int numTiles = (E + 63) / 64;
    int grid = numTiles < GRID_MAIN ? numTiles : GRID_MAIN;
    if (useNB) {
        int n8 = N * 8;
        node_conv_kernel<<<(n8 + 255) / 256, 256, 0, stream>>>(node_feats, nodeBF, n8);
        edge_mlp_kernel<<<grid, 256, 0, stream>>>(edge_feats, nodeBF, senders, receivers,
                                                  W1F, W2F, g1, b2, out, E, numTiles);
    } else {
        edge_mlp_fallback<<<grid, 256, 0, stream>>>(edge_feats, node_feats, senders, receivers,
                                                    W1F, W2F, g1, b2, out, E, numTiles);
    }
}

// Round 6
// 123.994 us; speedup vs baseline: 6.0236x; 1.0112x over previous
//
#include <hip/hip_runtime.h>
#include <hip/hip_bf16.h>

// EdgeBlock: out[e] = relu(concat(edge[e], node[recv[e]], node[send[e]], g) @ W1 + b1) @ W2 + b2
// Round 6 (on the working r5 structure):
//  - T14 async-stage: next tile's gathers issued into regs right after A_lds write,
//    idx prefetched 2 tiles ahead; loads complete under current tile's GEMMs
//  - raw s_barrier with lgkmcnt-only waits (no vmcnt drain -> prefetch survives barriers)
//  - frag-order h tile (16 KB): conflict-free GEMM2 reads, packed bf16x2 writes,
//    k-permutation sigma baked into W2F prep; LDS 41984 -> 40960 => 4 blocks/CU

typedef __bf16 bf16x8 __attribute__((ext_vector_type(8)));
typedef __bf16 bf16x2 __attribute__((ext_vector_type(2)));
typedef float f32x4 __attribute__((ext_vector_type(4)));

#define GRID_MAIN 2048
// ws layout:
//   [0, 49152)       W1F bf16 frag-order (as r5)
//   [49152, 65536)   W2F bf16 frag-order, physical-k slots with sigma^-1 baked in
//   [65536, 66048)   g1 f32 [128] = b1 + global_attr @ W1[192:256]
//   [66560, ...)     node_bf16 [N][64]
#define WS_NODEBF_OFF 66560

__global__ void prep_kernel(const float* __restrict__ W1, const float* __restrict__ b1,
                            const float* __restrict__ W2, const float* __restrict__ gattr,
                            __bf16* __restrict__ W1F, __bf16* __restrict__ W2F,
                            float* __restrict__ g1) {
    int tid = blockIdx.x * blockDim.x + threadIdx.x;
    if (tid < 128 * 192) {
        int n = tid / 192, k = tid % 192;
        int w = n >> 5, nt2 = (n >> 4) & 1, c = n & 15;
        int f = k >> 5, g = (k >> 3) & 3, j = k & 7;
        W1F[((((w * 2 + nt2) * 6 + f) * 64) + c + 16 * g) * 8 + j] = (__bf16)W1[k * 128 + n];
    } else if (tid < 128 * 192 + 64 * 128) {
        int t = tid - 128 * 192;
        int n = t / 128, p = t % 128;   // p = PHYSICAL k slot (h_frag column)
        int w = n >> 4, c = n & 15;
        int ks = p >> 5, g = (p >> 3) & 3, j = p & 7;
        // sigma: klog = w1*32 + half*16 + cc  ->  p = w1*32 + 2*cc + half
        int klog = (p >> 5) * 32 + (p & 1) * 16 + ((p >> 1) & 15);
        W2F[(((w * 4 + ks) * 64) + c + 16 * g) * 8 + j] = (__bf16)W2[klog * 64 + n];
    } else if (tid < 128 * 192 + 64 * 128 + 128) {
        int n = tid - (128 * 192 + 64 * 128);
        float acc = b1[n];
        for (int j = 0; j < 64; ++j) acc += gattr[j] * W1[(192 + j) * 128 + n];
        g1[n] = acc;
    }
}

__global__ __launch_bounds__(256) void node_conv_kernel(const float* __restrict__ nf,
                                                        __bf16* __restrict__ nb, int n8) {
    int t = blockIdx.x * blockDim.x + threadIdx.x;
    if (t < n8) {
        f32x4 a = *(const f32x4*)(nf + (long)t * 8);
        f32x4 b = *(const f32x4*)(nf + (long)t * 8 + 4);
        bf16x8 o;
#pragma unroll
        for (int j = 0; j < 4; ++j) { o[j] = (__bf16)a[j]; o[4 + j] = (__bf16)b[j]; }
        *(bf16x8*)(nb + (long)t * 8) = o;
    }
}

__device__ __forceinline__ f32x4 mk4(float v) {
    f32x4 r; r[0] = v; r[1] = v; r[2] = v; r[3] = v; return r;
}

__device__ __forceinline__ bf16x8 cvt8(f32x4 lo, f32x4 hi) {
    bf16x8 t;
#pragma unroll
    for (int j = 0; j < 4; ++j) { t[j] = (__bf16)lo[j]; t[4 + j] = (__bf16)hi[j]; }
    return t;
}

__global__ __launch_bounds__(256) void edge_mlp_kernel(
    const float* __restrict__ edge_feats, const __bf16* __restrict__ node_bf,
    const int* __restrict__ senders, const int* __restrict__ receivers,
    const __bf16* __restrict__ W1F, const __bf16* __restrict__ W2F,
    const float* __restrict__ g1, const float* __restrict__ b2,
    float* __restrict__ out, int E, int numTiles)
{
    // frag-order A tile: [mt=4][f=6][lane=64] x 16B  (24 KB)
    __shared__ __bf16 A_lds[4 * 6 * 64 * 8];
    // frag-order h tile: [mt=4][ks=4][lane'=64] x 16B (16 KB); lane' = c*4+g
    __shared__ __bf16 h_frag[4 * 4 * 64 * 8];

    const int lane = threadIdx.x & 63;
    const int w    = threadIdx.x >> 6;
    const int c    = lane & 15;
    const int g    = lane >> 4;
    const int G    = gridDim.x;

    // ---- pinned weights: 16 coalesced dwordx4 loads, once per block ----
    bf16x8 wb1[2][6];
#pragma unroll
    for (int nt2 = 0; nt2 < 2; ++nt2)
#pragma unroll
        for (int f = 0; f < 6; ++f)
            wb1[nt2][f] = *(const bf16x8*)(W1F + (((w * 2 + nt2) * 6 + f) * 64 + lane) * 8);
    bf16x8 wb2[4];
#pragma unroll
    for (int ks = 0; ks < 4; ++ks)
        wb2[ks] = *(const bf16x8*)(W2F + ((w * 4 + ks) * 64 + lane) * 8);
    const float g1v0 = g1[w * 32 + c];
    const float g1v1 = g1[w * 32 + 16 + c];
    const float b2v  = b2[w * 16 + c];

    // ---- prologue: stage tile blockIdx.x; idx for tile +G ----
    bf16x8 snr0, snr1, sns0, sns1;
    f32x4 se0, se1, se2, se3;
    int iR, iS;
    {
        long rc = (long)blockIdx.x * 64 + w * 16 + c;
        if (rc > (long)E - 1) rc = (long)E - 1;
        iR = receivers[rc]; iS = senders[rc];
        const __bf16* pr = node_bf + ((long)iR << 6) + g * 8;
        const __bf16* ps = node_bf + ((long)iS << 6) + g * 8;
        snr0 = *(const bf16x8*)(pr);
        snr1 = *(const bf16x8*)(pr + 32);
        sns0 = *(const bf16x8*)(ps);
        sns1 = *(const bf16x8*)(ps + 32);
        const float* pe = edge_feats + (rc << 6) + g * 8;
        se0 = *(const f32x4*)(pe);      se1 = *(const f32x4*)(pe + 4);
        se2 = *(const f32x4*)(pe + 32); se3 = *(const f32x4*)(pe + 36);
        if (blockIdx.x + G < numTiles) {
            long rc2 = (long)(blockIdx.x + G) * 64 + w * 16 + c;
            if (rc2 > (long)E - 1) rc2 = (long)E - 1;
            iR = receivers[rc2]; iS = senders[rc2];
        }
    }

    for (int t = blockIdx.x; t < numTiles; t += G) {
        // ---- stage -> A_lds (compiler inserts counted vmcnt for stage regs) ----
        __bf16* ab = A_lds + w * 6 * 512 + lane * 8;
        *(bf16x8*)(ab)        = cvt8(se0, se1);
        *(bf16x8*)(ab + 512)  = cvt8(se2, se3);
        *(bf16x8*)(ab + 1024) = snr0;
        *(bf16x8*)(ab + 1536) = snr1;
        *(bf16x8*)(ab + 2048) = sns0;
        *(bf16x8*)(ab + 2560) = sns1;

        // ---- T14: issue NEXT tile's loads into stage regs; idx 2 ahead ----
        const int tn = t + G;
        if (tn < numTiles) {
            const __bf16* pr = node_bf + ((long)iR << 6) + g * 8;
            const __bf16* ps = node_bf + ((long)iS << 6) + g * 8;
            snr0 = *(const bf16x8*)(pr);
            snr1 = *(const bf16x8*)(pr + 32);
            sns0 = *(const bf16x8*)(ps);
            sns1 = *(const bf16x8*)(ps + 32);
            long rce = (long)tn * 64 + w * 16 + c;
            if (rce > (long)E - 1) rce = (long)E - 1;
            const float* pe = edge_feats + (rce << 6) + g * 8;
            se0 = *(const f32x4*)(pe);      se1 = *(const f32x4*)(pe + 4);
            se2 = *(const f32x4*)(pe + 32); se3 = *(const f32x4*)(pe + 36);
            if (tn + G < numTiles) {
                long rc2 = (long)(tn + G) * 64 + w * 16 + c;
                if (rc2 > (long)E - 1) rc2 = (long)E - 1;
                iR = receivers[rc2]; iS = senders[rc2];
            }
        }
        __builtin_amdgcn_sched_barrier(0);

        // barrier 1: A_lds visible; VMEM prefetch stays in flight (no vmcnt drain)
        asm volatile("s_waitcnt lgkmcnt(0)" ::: "memory");
        __builtin_amdgcn_s_barrier();

        // ---- GEMM1: wave owns hidden cols [w*32, w*32+32) for all 64 edges ----
        f32x4 acc0[4], acc1[4];
#pragma unroll
        for (int mt = 0; mt < 4; ++mt) { acc0[mt] = mk4(g1v0); acc1[mt] = mk4(g1v1); }
#pragma unroll
        for (int mt = 0; mt < 4; ++mt)
#pragma unroll
            for (int f = 0; f < 6; ++f) {
                bf16x8 a = *(const bf16x8*)(A_lds + ((mt * 6 + f) * 64 + lane) * 8);
                acc0[mt] = __builtin_amdgcn_mfma_f32_16x16x32_bf16(a, wb1[0][f], acc0[mt], 0, 0, 0);
                acc1[mt] = __builtin_amdgcn_mfma_f32_16x16x32_bf16(a, wb1[1][f], acc1[mt], 0, 0, 0);
            }

        // ---- relu -> frag-order h (packed bf16x2; physical col = w*32 + 2c + half) ----
#pragma unroll
        for (int mt = 0; mt < 4; ++mt)
#pragma unroll
            for (int r = 0; r < 4; ++r) {
                float v0 = acc0[mt][r]; v0 = v0 > 0.f ? v0 : 0.f;
                float v1 = acc1[mt][r]; v1 = v1 > 0.f ? v1 : 0.f;
                bf16x2 pk; pk[0] = (__bf16)v0; pk[1] = (__bf16)v1;
                *(bf16x2*)&h_frag[(((mt * 4 + w) * 64 + (g * 4 + r) * 4 + (c >> 2)) << 3)
                                  + ((c & 3) << 1)] = pk;
            }

        // barrier 2: h visible
        asm volatile("s_waitcnt lgkmcnt(0)" ::: "memory");
        __builtin_amdgcn_s_barrier();

        // ---- GEMM2: wave owns out cols [w*16, w*16+16); reads lane-linear frags ----
        f32x4 acc2[4];
#pragma unroll
        for (int mt = 0; mt < 4; ++mt) acc2[mt] = mk4(b2v);
#pragma unroll
        for (int mt = 0; mt < 4; ++mt)
#pragma unroll
            for (int ks = 0; ks < 4; ++ks) {
                bf16x8 ah = *(const bf16x8*)&h_frag[((mt * 4 + ks) * 64 + c * 4 + g) * 8];
                acc2[mt] = __builtin_amdgcn_mfma_f32_16x16x32_bf16(ah, wb2[ks], acc2[mt], 0, 0, 0);
            }

        // ---- stores (4 x 64B segments per instr) ----
#pragma unroll
        for (int mt = 0; mt < 4; ++mt)
#pragma unroll
            for (int r = 0; r < 4; ++r) {
                long orow = (long)t * 64 + mt * 16 + g * 4 + r;
                if (orow < E) out[orow * 64 + w * 16 + c] = acc2[mt][r];
            }

        // barrier 3: LDS reads done before next iteration's writes (lgkm only)
        asm volatile("s_waitcnt lgkmcnt(0)" ::: "memory");
        __builtin_amdgcn_s_barrier();
    }
}

// fallback (ws too small for node table): r5 structure, f32 gathers, frag-order h
__global__ __launch_bounds__(256) void edge_mlp_fallback(
    const float* __restrict__ edge_feats, const float* __restrict__ node_feats,
    const int* __restrict__ senders, const int* __restrict__ receivers,
    const __bf16* __restrict__ W1F, const __bf16* __restrict__ W2F,
    const float* __restrict__ g1, const float* __restrict__ b2,
    float* __restrict__ out, int E, int numTiles)
{
    __shared__ __bf16 A_lds[4 * 6 * 64 * 8];
    __shared__ __bf16 h_frag[4 * 4 * 64 * 8];
    const int lane = threadIdx.x & 63;
    const int w = threadIdx.x >> 6;
    const int c = lane & 15;
    const int g = lane >> 4;
    const int G = gridDim.x;

    bf16x8 wb1[2][6];
#pragma unroll
    for (int nt2 = 0; nt2 < 2; ++nt2)
#pragma unroll
        for (int f = 0; f < 6; ++f)
            wb1[nt2][f] = *(const bf16x8*)(W1F + (((w * 2 + nt2) * 6 + f) * 64 + lane) * 8);
    bf16x8 wb2[4];
#pragma unroll
    for (int ks = 0; ks < 4; ++ks)
        wb2[ks] = *(const bf16x8*)(W2F + ((w * 4 + ks) * 64 + lane) * 8);
    const float g1v0 = g1[w * 32 + c];
    const float g1v1 = g1[w * 32 + 16 + c];
    const float b2v  = b2[w * 16 + c];

    for (int t = blockIdx.x; t < numTiles; t += G) {
        long rowc = (long)t * 64 + w * 16 + c;
        if (rowc > (long)E - 1) rowc = (long)E - 1;
        int iR = receivers[rowc], iS = senders[rowc];
        const float* pr = node_feats + ((long)iR << 6) + g * 8;
        const float* ps = node_feats + ((long)iS << 6) + g * 8;
        const float* pe = edge_feats + (rowc << 6) + g * 8;
        f32x4 e0a = *(const f32x4*)(pe),      e0b = *(const f32x4*)(pe + 4);
        f32x4 e1a = *(const f32x4*)(pe + 32), e1b = *(const f32x4*)(pe + 36);
        f32x4 r0a = *(const f32x4*)(pr),      r0b = *(const f32x4*)(pr + 4);
        f32x4 r1a = *(const f32x4*)(pr + 32), r1b = *(const f32x4*)(pr + 36);
        f32x4 s0a = *(const f32x4*)(ps),      s0b = *(const f32x4*)(ps + 4);
        f32x4 s1a = *(const f32x4*)(ps + 32), s1b = *(const f32x4*)(ps + 36);

        __bf16* ab = A_lds + w * 6 * 512 + lane * 8;
        *(bf16x8*)(ab)        = cvt8(e0a, e0b);
        *(bf16x8*)(ab + 512)  = cvt8(e1a, e1b);
        *(bf16x8*)(ab + 1024) = cvt8(r0a, r0b);
        *(bf16x8*)(ab + 1536) = cvt8(r1a, r1b);
        *(bf16x8*)(ab + 2048) = cvt8(s0a, s0b);
        *(bf16x8*)(ab + 2560) = cvt8(s1a, s1b);
        __syncthreads();

        f32x4 acc0[4], acc1[4];
#pragma unroll
        for (int mt = 0; mt < 4; ++mt) { acc0[mt] = mk4(g1v0); acc1[mt] = mk4(g1v1); }
#pragma unroll
        for (int mt = 0; mt < 4; ++mt)
#pragma unroll
            for (int f = 0; f < 6; ++f) {
                bf16x8 a = *(const bf16x8*)(A_lds + ((mt * 6 + f) * 64 + lane) * 8);
                acc0[mt] = __builtin_amdgcn_mfma_f32_16x16x32_bf16(a, wb1[0][f], acc0[mt], 0, 0, 0);
                acc1[mt] = __builtin_amdgcn_mfma_f32_16x16x32_bf16(a, wb1[1][f], acc1[mt], 0, 0, 0);
            }
#pragma unroll
        for (int mt = 0; mt < 4; ++mt)
#pragma unroll
            for (int r = 0; r < 4; ++r) {
                float v0 = acc0[mt][r]; v0 = v0 > 0.f ? v0 : 0.f;
                float v1 = acc1[mt][r]; v1 = v1 > 0.f ? v1 : 0.f;
                bf16x2 pk; pk[0] = (__bf16)v0; pk[1] = (__bf16)v1;
                *(bf16x2*)&h_frag[(((mt * 4 + w) * 64 + (g * 4 + r) * 4 + (c >> 2)) << 3)
                                  + ((c & 3) << 1)] = pk;
            }
        __syncthreads();

        f32x4 acc2[4];
#pragma unroll
        for (int mt = 0; mt < 4; ++mt) acc2[mt] = mk4(b2v);
#pragma unroll
        for (int mt = 0; mt < 4; ++mt)
#pragma unroll
            for (int ks = 0; ks < 4; ++ks) {
                bf16x8 ah = *(const bf16x8*)&h_frag[((mt * 4 + ks) * 64 + c * 4 + g) * 8];
                acc2[mt] = __builtin_amdgcn_mfma_f32_16x16x32_bf16(ah, wb2[ks], acc2[mt], 0, 0, 0);
            }
#pragma unroll
        for (int mt = 0; mt < 4; ++mt)
#pragma unroll
            for (int r = 0; r < 4; ++r) {
                long orow = (long)t * 64 + mt * 16 + g * 4 + r;
                if (orow < E) out[orow * 64 + w * 16 + c] = acc2[mt][r];
            }
        __syncthreads();
    }
}

extern "C" void kernel_launch(void* const* d_in, const int* in_sizes, int n_in,
                              void* d_out, int out_size, void* d_ws, size_t ws_size,
                              hipStream_t stream) {
    const float* edge_feats = (const float*)d_in[0];
    const float* node_feats = (const float*)d_in[1];
    const float* gattr      = (const float*)d_in[2];
    const int*   senders    = (const int*)d_in[3];
    const int*   receivers  = (const int*)d_in[4];
    const float* W1         = (const float*)d_in[5];
    const float* b1         = (const float*)d_in[6];
    const float* W2         = (const float*)d_in[7];
    const float* b2         = (const float*)d_in[8];
    float* out = (float*)d_out;

    const int E = in_sizes[3];        // N_EDGES
    const int N = in_sizes[1] / 64;   // N_NODES

    char* ws = (char*)d_ws;
    __bf16* W1F = (__bf16*)ws;
    __bf16* W2F = (__bf16*)(ws + 49152);
    float*  g1  = (float*)(ws + 49152 + 16384);
    __bf16* nodeBF = (__bf16*)(ws + WS_NODEBF_OFF);

    const size_t ws_needed = (size_t)WS_NODEBF_OFF + (size_t)N * 64 * 2;
    const bool useNB = ws_size >= ws_needed;

    int prep_total = 128 * 192 + 64 * 128 + 128;
    prep_kernel<<<(prep_total + 255) / 256, 256, 0, stream>>>(W1, b1, W2, gattr, W1F, W2F, g1);

    const int numTiles = (E + 63) / 64;
    int grid = numTiles < GRID_MAIN ? numTiles : GRID_MAIN;
    if (useNB) {
        int n8 = N * 8;
        node_conv_kernel<<<(n8 + 255) / 256, 256, 0, stream>>>(node_feats, nodeBF, n8);
        edge_mlp_kernel<<<grid, 256, 0, stream>>>(edge_feats, nodeBF, senders, receivers,
                                                  W1F, W2F, g1, b2, out, E, numTiles);
    } else {
        edge_mlp_fallback<<<grid, 256, 0, stream>>>(edge_feats, node_feats, senders, receivers,
                                                    W1F, W2F, g1, b2, out, E, numTiles);
    }
}